// Round 1
// baseline (6495.573 us; speedup 1.0000x reference)
//
#include <hip/hip_runtime.h>
#include <hip/hip_bf16.h>
#include <math.h>

// Problem constants (GroupedQueryAttention: B=2,T=2048,E=2048,H=32,KV=8,D=64,R=4)
#define B_   2
#define T_   2048
#define E_   2048
#define H_   32
#define KV_  8
#define D_   64
#define NROW (B_*T_)          // 4096 rows of x
#define QW   (H_*D_)          // 2048
#define KW   (KV_*D_)         // 512

// ---------------------------------------------------------------------------
// Tiled fp32 GEMM: C[M x N] = A[M x K] * W[K x N], row-major.
// BM=BN=128, BK=16, 256 threads, 8x8 micro-tile per thread.
// ---------------------------------------------------------------------------
#define BM 128
#define BN 128
#define BK 16
#define LPAD 132   // padded leading dim for LDS tiles (keeps 16B alignment, breaks pow2 stride)

__device__ __forceinline__
void gemm_tile(const float* __restrict__ A, const float* __restrict__ W,
               float* __restrict__ C, int N, int K, int brow, int bcol,
               float (*As)[LPAD], float (*Bs)[LPAD])
{
    const int tid = threadIdx.x;
    const int tr = tid >> 4;      // 0..15
    const int tc = tid & 15;      // 0..15
    float acc[8][8] = {};

    for (int k0 = 0; k0 < K; k0 += BK) {
        // Load A tile (BM x BK) transposed into As[k][m]. 512 float4, 2/thread.
#pragma unroll
        for (int i = 0; i < 2; ++i) {
            int li = tid + i * 256;        // float4 index
            int r  = li >> 2;              // row in tile (4 float4 per row)
            int kq = li & 3;
            float4 v = *reinterpret_cast<const float4*>(A + (size_t)(brow + r) * K + k0 + kq * 4);
            As[kq*4+0][r] = v.x; As[kq*4+1][r] = v.y;
            As[kq*4+2][r] = v.z; As[kq*4+3][r] = v.w;
        }
        // Load B tile (BK x BN). 512 float4, 2/thread, coalesced.
#pragma unroll
        for (int i = 0; i < 2; ++i) {
            int li = tid + i * 256;
            int r  = li >> 5;              // 32 float4 per row
            int cq = li & 31;
            *reinterpret_cast<float4*>(&Bs[r][cq*4]) =
                *reinterpret_cast<const float4*>(W + (size_t)(k0 + r) * N + bcol + cq * 4);
        }
        __syncthreads();
#pragma unroll
        for (int k = 0; k < BK; ++k) {
            float a[8], b[8];
            *reinterpret_cast<float4*>(a)     = *reinterpret_cast<const float4*>(&As[k][tr*8]);
            *reinterpret_cast<float4*>(a + 4) = *reinterpret_cast<const float4*>(&As[k][tr*8+4]);
            *reinterpret_cast<float4*>(b)     = *reinterpret_cast<const float4*>(&Bs[k][tc*8]);
            *reinterpret_cast<float4*>(b + 4) = *reinterpret_cast<const float4*>(&Bs[k][tc*8+4]);
#pragma unroll
            for (int y = 0; y < 8; ++y)
#pragma unroll
                for (int x = 0; x < 8; ++x)
                    acc[y][x] = fmaf(a[y], b[x], acc[y][x]);
        }
        __syncthreads();
    }
    // Epilogue: 8 rows x 2 float4 per thread.
#pragma unroll
    for (int y = 0; y < 8; ++y) {
        float* dst = C + (size_t)(brow + tr*8 + y) * N + bcol + tc*8;
        *reinterpret_cast<float4*>(dst)     = make_float4(acc[y][0], acc[y][1], acc[y][2], acc[y][3]);
        *reinterpret_cast<float4*>(dst + 4) = make_float4(acc[y][4], acc[y][5], acc[y][6], acc[y][7]);
    }
}

// Fused QKV projection: grid.x = 16 (Q tiles) + 4 (K tiles) + 4 (V tiles) = 24, grid.y = 32.
__global__ __launch_bounds__(256)
void gemm_qkv(const float* __restrict__ x,
              const float* __restrict__ Wq, const float* __restrict__ Wk,
              const float* __restrict__ Wv,
              float* __restrict__ Q, float* __restrict__ K, float* __restrict__ V)
{
    __shared__ float As[BK][LPAD];
    __shared__ float Bs[BK][LPAD];
    const int bx = blockIdx.x;
    const int brow = blockIdx.y * BM;
    const float* W; float* C; int N; int bcol;
    if (bx < 16)      { W = Wq; C = Q; N = QW; bcol = bx * BN; }
    else if (bx < 20) { W = Wk; C = K; N = KW; bcol = (bx - 16) * BN; }
    else              { W = Wv; C = V; N = KW; bcol = (bx - 20) * BN; }
    gemm_tile(x, W, C, N, E_, brow, bcol, As, Bs);
}

// Generic single-output GEMM (used for the output projection).
__global__ __launch_bounds__(256)
void gemm128(const float* __restrict__ A, const float* __restrict__ W,
             float* __restrict__ C, int N, int K)
{
    __shared__ float As[BK][LPAD];
    __shared__ float Bs[BK][LPAD];
    gemm_tile(A, W, C, N, K, blockIdx.y * BM, blockIdx.x * BN, As, Bs);
}

// ---------------------------------------------------------------------------
// RoPE applied in-place to Q (width 2048) and K (width 512).
// One thread per (row, head, pair). freq_cis layout: (T, 32, 2) fp32.
// ---------------------------------------------------------------------------
#define QPAIRS (NROW * H_  * 32)   // 4,194,304
#define KPAIRS (NROW * KV_ * 32)   // 1,048,576
#define TPAIRS (QPAIRS + KPAIRS)   // 5,242,880

__global__ __launch_bounds__(256)
void rope_kernel(float* __restrict__ Qb, float* __restrict__ Kb,
                 const float* __restrict__ fc)
{
    int idx = blockIdx.x * 256 + threadIdx.x;
    if (idx >= TPAIRS) return;
    float* buf; int n, hd, width;
    if (idx < QPAIRS) { buf = Qb; n = idx >> 10; hd = idx & 1023; width = QW; }  // H*32 = 1024
    else { int i2 = idx - QPAIRS; buf = Kb; n = i2 >> 8; hd = i2 & 255; width = KW; } // KV*32 = 256
    const int pair = hd & 31;
    const int head = hd >> 5;
    const int t = n & (T_ - 1);
    const float c = fc[t * 64 + pair * 2];
    const float s = fc[t * 64 + pair * 2 + 1];
    float* p = buf + (size_t)n * width + head * 64 + pair * 2;
    float2 ab = *reinterpret_cast<const float2*>(p);
    float2 r;
    r.x = ab.x * c - ab.y * s;
    r.y = ab.x * s + ab.y * c;
    *reinterpret_cast<float2*>(p) = r;
}

// ---------------------------------------------------------------------------
// Flash attention, fp32, causal, GQA (R=4).
// grid = (T/64, H, B), 64 threads (1 wave). Each thread owns one q row.
// K then V staged through one 16KB LDS buffer; online softmax in registers.
// ---------------------------------------------------------------------------
__global__ __launch_bounds__(64)
void attn_fp32(const float* __restrict__ Qb, const float* __restrict__ Kb,
               const float* __restrict__ Vb, float* __restrict__ Ob)
{
    __shared__ float kv[64][64];
    const int qt = blockIdx.x, h = blockIdx.y, b = blockIdx.z;
    const int kvh = h >> 2;                       // R = 4
    const int lane = threadIdx.x;
    const int qg = qt * 64 + lane;                // global q position in [0,T)
    const float* qptr = Qb + ((size_t)(b * T_) + qg) * QW + h * D_;

    float q[64], o[64] = {}, s[64];
#pragma unroll
    for (int i = 0; i < 16; ++i)
        *reinterpret_cast<float4*>(&q[i * 4]) = *reinterpret_cast<const float4*>(qptr + i * 4);

    float m = -INFINITY, l = 0.f;

    for (int j = 0; j <= qt; ++j) {
        __syncthreads();   // protect kv[] against previous iteration's readers
        const float* kbase = Kb + ((size_t)(b * T_) + j * 64) * KW + kvh * D_;
#pragma unroll
        for (int i = 0; i < 16; ++i) {
            int li = lane + i * 64, r = li >> 4, cq = li & 15;
            *reinterpret_cast<float4*>(&kv[r][cq * 4]) =
                *reinterpret_cast<const float4*>(kbase + (size_t)r * KW + cq * 4);
        }
        __syncthreads();

        // S = q . K^T * 1/sqrt(D); all lanes broadcast-read the same K row.
#pragma unroll
        for (int c = 0; c < 64; ++c) {
            float acc = 0.f;
#pragma unroll
            for (int d = 0; d < 64; ++d) acc = fmaf(q[d], kv[c][d], acc);
            s[c] = acc * 0.125f;
        }
        if (j == qt) {   // diagonal tile: causal mask
#pragma unroll
            for (int c = 0; c < 64; ++c)
                if (j * 64 + c > qg) s[c] = -INFINITY;
        }
        float tmax = s[0];
#pragma unroll
        for (int c = 1; c < 64; ++c) tmax = fmaxf(tmax, s[c]);
        const float mnew = fmaxf(m, tmax);
        const float scale = __expf(m - mnew);     // exp(-inf)=0 on first tile
        float psum = 0.f;
#pragma unroll
        for (int c = 0; c < 64; ++c) { s[c] = __expf(s[c] - mnew); psum += s[c]; }
        l = l * scale + psum;
        m = mnew;
#pragma unroll
        for (int d = 0; d < 64; ++d) o[d] *= scale;

        __syncthreads();
        const float* vbase = Vb + ((size_t)(b * T_) + j * 64) * KW + kvh * D_;
#pragma unroll
        for (int i = 0; i < 16; ++i) {
            int li = lane + i * 64, r = li >> 4, cq = li & 15;
            *reinterpret_cast<float4*>(&kv[r][cq * 4]) =
                *reinterpret_cast<const float4*>(vbase + (size_t)r * KW + cq * 4);
        }
        __syncthreads();
#pragma unroll
        for (int c = 0; c < 64; ++c) {
            const float p = s[c];
#pragma unroll
            for (int d = 0; d < 64; ++d) o[d] = fmaf(p, kv[c][d], o[d]);
        }
    }

    const float inv = 1.f / l;
    float* optr = Ob + ((size_t)(b * T_) + qg) * QW + h * D_;
#pragma unroll
    for (int i = 0; i < 16; ++i) {
        *reinterpret_cast<float4*>(optr + i * 4) =
            make_float4(o[i*4] * inv, o[i*4+1] * inv, o[i*4+2] * inv, o[i*4+3] * inv);
    }
}

// ---------------------------------------------------------------------------
// Launch. Workspace layout (needs 80 MB):
//   Q: 4096x2048 f32 (32 MB) | K: 4096x512 (8 MB) | V: 4096x512 (8 MB) | O: 4096x2048 (32 MB)
// ---------------------------------------------------------------------------
extern "C" void kernel_launch(void* const* d_in, const int* in_sizes, int n_in,
                              void* d_out, int out_size, void* d_ws, size_t ws_size,
                              hipStream_t stream)
{
    const float* x  = (const float*)d_in[0];
    const float* fc = (const float*)d_in[1];
    const float* Wq = (const float*)d_in[2];
    const float* Wk = (const float*)d_in[3];
    const float* Wv = (const float*)d_in[4];
    const float* Wo = (const float*)d_in[5];
    float* out = (float*)d_out;

    char* ws = (char*)d_ws;
    float* Q = (float*)(ws);
    float* K = (float*)(ws + 33554432);
    float* V = (float*)(ws + 41943040);
    float* O = (float*)(ws + 50331648);

    // 1) QKV projections (fused launch): x(4096x2048) @ {Wq,Wk,Wv}
    gemm_qkv<<<dim3(24, 32), 256, 0, stream>>>(x, Wq, Wk, Wv, Q, K, V);

    // 2) RoPE in-place on Q and K
    rope_kernel<<<TPAIRS / 256, 256, 0, stream>>>(Q, K, fc);

    // 3) Causal GQA flash attention -> O (B,T,H,D)
    attn_fp32<<<dim3(T_ / 64, H_, B_), 64, 0, stream>>>(Q, K, V, O);

    // 4) Output projection: O(4096x2048) @ Wo(2048x2048) -> out
    gemm128<<<dim3(QW / BN, NROW / BM), 256, 0, stream>>>(O, Wo, out, E_, E_);
}

// Round 2
// 1607.735 us; speedup vs baseline: 4.0402x; 4.0402x over previous
//
#include <hip/hip_runtime.h>
#include <hip/hip_bf16.h>
#include <math.h>

// Problem constants (GroupedQueryAttention: B=2,T=2048,E=2048,H=32,KV=8,D=64,R=4)
#define B_   2
#define T_   2048
#define E_   2048
#define H_   32
#define KV_  8
#define D_   64
#define NROW (B_*T_)          // 4096 rows of x
#define QW   (H_*D_)          // 2048
#define KW   (KV_*D_)         // 512

typedef __attribute__((ext_vector_type(8))) short short8;
typedef __attribute__((ext_vector_type(4))) float f32x4;

// ---------------------------------------------------------------------------
// Tiled fp32 GEMM: C[M x N] = A[M x K] * W[K x N], row-major.
// BM=BN=128, BK=16, 256 threads, 8x8 micro-tile per thread.
// ---------------------------------------------------------------------------
#define BM 128
#define BN 128
#define BK 16
#define LPAD 132

__device__ __forceinline__
void gemm_tile(const float* __restrict__ A, const float* __restrict__ W,
               float* __restrict__ C, int N, int K, int brow, int bcol,
               float (*As)[LPAD], float (*Bs)[LPAD])
{
    const int tid = threadIdx.x;
    const int tr = tid >> 4;      // 0..15
    const int tc = tid & 15;      // 0..15
    float acc[8][8] = {};

    for (int k0 = 0; k0 < K; k0 += BK) {
#pragma unroll
        for (int i = 0; i < 2; ++i) {
            int li = tid + i * 256;
            int r  = li >> 2;
            int kq = li & 3;
            float4 v = *reinterpret_cast<const float4*>(A + (size_t)(brow + r) * K + k0 + kq * 4);
            As[kq*4+0][r] = v.x; As[kq*4+1][r] = v.y;
            As[kq*4+2][r] = v.z; As[kq*4+3][r] = v.w;
        }
#pragma unroll
        for (int i = 0; i < 2; ++i) {
            int li = tid + i * 256;
            int r  = li >> 5;
            int cq = li & 31;
            *reinterpret_cast<float4*>(&Bs[r][cq*4]) =
                *reinterpret_cast<const float4*>(W + (size_t)(k0 + r) * N + bcol + cq * 4);
        }
        __syncthreads();
#pragma unroll
        for (int k = 0; k < BK; ++k) {
            float a[8], b[8];
            *reinterpret_cast<float4*>(a)     = *reinterpret_cast<const float4*>(&As[k][tr*8]);
            *reinterpret_cast<float4*>(a + 4) = *reinterpret_cast<const float4*>(&As[k][tr*8+4]);
            *reinterpret_cast<float4*>(b)     = *reinterpret_cast<const float4*>(&Bs[k][tc*8]);
            *reinterpret_cast<float4*>(b + 4) = *reinterpret_cast<const float4*>(&Bs[k][tc*8+4]);
#pragma unroll
            for (int y = 0; y < 8; ++y)
#pragma unroll
                for (int x = 0; x < 8; ++x)
                    acc[y][x] = fmaf(a[y], b[x], acc[y][x]);
        }
        __syncthreads();
    }
#pragma unroll
    for (int y = 0; y < 8; ++y) {
        float* dst = C + (size_t)(brow + tr*8 + y) * N + bcol + tc*8;
        *reinterpret_cast<float4*>(dst)     = make_float4(acc[y][0], acc[y][1], acc[y][2], acc[y][3]);
        *reinterpret_cast<float4*>(dst + 4) = make_float4(acc[y][4], acc[y][5], acc[y][6], acc[y][7]);
    }
}

__global__ __launch_bounds__(256)
void gemm_qkv(const float* __restrict__ x,
              const float* __restrict__ Wq, const float* __restrict__ Wk,
              const float* __restrict__ Wv,
              float* __restrict__ Q, float* __restrict__ K, float* __restrict__ V)
{
    __shared__ float As[BK][LPAD];
    __shared__ float Bs[BK][LPAD];
    const int bx = blockIdx.x;
    const int brow = blockIdx.y * BM;
    const float* W; float* C; int N; int bcol;
    if (bx < 16)      { W = Wq; C = Q; N = QW; bcol = bx * BN; }
    else if (bx < 20) { W = Wk; C = K; N = KW; bcol = (bx - 16) * BN; }
    else              { W = Wv; C = V; N = KW; bcol = (bx - 20) * BN; }
    gemm_tile(x, W, C, N, E_, brow, bcol, As, Bs);
}

__global__ __launch_bounds__(256)
void gemm128(const float* __restrict__ A, const float* __restrict__ W,
             float* __restrict__ C, int N, int K)
{
    __shared__ float As[BK][LPAD];
    __shared__ float Bs[BK][LPAD];
    gemm_tile(A, W, C, N, K, blockIdx.y * BM, blockIdx.x * BN, As, Bs);
}

// ---------------------------------------------------------------------------
// prep_qk: RoPE (fp32) + cast to bf16, re-layout head-major.
//   Qbf: [b][h][t][64]   Kbf: [b][kvh][t][64]
// one thread per (row, head, pair); pair index fastest -> coalesced.
// ---------------------------------------------------------------------------
#define QPAIRS (NROW * H_  * 32)   // 4,194,304
#define KPAIRS (NROW * KV_ * 32)   // 1,048,576
#define TPAIRS (QPAIRS + KPAIRS)   // 5,242,880

__global__ __launch_bounds__(256)
void prep_qk(const float* __restrict__ Qf, const float* __restrict__ Kf,
             const float* __restrict__ fc,
             __hip_bfloat16* __restrict__ Qb, __hip_bfloat16* __restrict__ Kb)
{
    int idx = blockIdx.x * 256 + threadIdx.x;
    if (idx < QPAIRS) {
        // idx = ((b*H + h)*T + t)*32 + p
        int p = idx & 31;
        int t = (idx >> 5) & (T_ - 1);
        int bh = idx >> 16;                 // T*32 = 65536
        int h = bh & (H_ - 1), b = bh >> 5;
        float2 ab = *reinterpret_cast<const float2*>(Qf + (size_t)(b * T_ + t) * QW + h * 64 + p * 2);
        float c = fc[t * 64 + p * 2], s = fc[t * 64 + p * 2 + 1];
        __hip_bfloat16 o0 = __float2bfloat16(ab.x * c - ab.y * s);
        __hip_bfloat16 o1 = __float2bfloat16(ab.x * s + ab.y * c);
        ushort2 pk;
        pk.x = *reinterpret_cast<unsigned short*>(&o0);
        pk.y = *reinterpret_cast<unsigned short*>(&o1);
        *reinterpret_cast<ushort2*>(Qb + (size_t)idx * 2) = pk;   // idx*2 == ((b*H+h)*T+t)*64 + 2p
    } else {
        int i2 = idx - QPAIRS;              // ((b*KV + kh)*T + t)*32 + p
        int p = i2 & 31;
        int t = (i2 >> 5) & (T_ - 1);
        int bk = i2 >> 16;
        int kh = bk & 7, b = bk >> 3;
        float2 ab = *reinterpret_cast<const float2*>(Kf + (size_t)(b * T_ + t) * KW + kh * 64 + p * 2);
        float c = fc[t * 64 + p * 2], s = fc[t * 64 + p * 2 + 1];
        __hip_bfloat16 o0 = __float2bfloat16(ab.x * c - ab.y * s);
        __hip_bfloat16 o1 = __float2bfloat16(ab.x * s + ab.y * c);
        ushort2 pk;
        pk.x = *reinterpret_cast<unsigned short*>(&o0);
        pk.y = *reinterpret_cast<unsigned short*>(&o1);
        *reinterpret_cast<ushort2*>(Kb + (size_t)i2 * 2) = pk;
    }
}

// ---------------------------------------------------------------------------
// transpose_v: V fp32 [b t][kvh d] -> VT bf16 [b][kvh][d][t]  (64x64 LDS tiles)
// ---------------------------------------------------------------------------
__global__ __launch_bounds__(256)
void transpose_v(const float* __restrict__ Vf, __hip_bfloat16* __restrict__ VT)
{
    __shared__ float tile[64][65];
    const int t0 = blockIdx.x * 64;
    const int bk = blockIdx.y;              // b*KV + kvh
    const int b = bk >> 3, kh = bk & 7;
    const int tid = threadIdx.x;
    const int c = tid & 63, rbase = tid >> 6;
#pragma unroll
    for (int i = 0; i < 16; ++i) {
        int r = rbase + i * 4;
        tile[r][c] = Vf[(size_t)(b * T_ + t0 + r) * KW + kh * 64 + c];
    }
    __syncthreads();
#pragma unroll
    for (int i = 0; i < 16; ++i) {
        int d = rbase + i * 4;
        VT[((size_t)bk * 64 + d) * T_ + t0 + c] = __float2bfloat16(tile[c][d]);
    }
}

// ---------------------------------------------------------------------------
// Flash attention, bf16 MFMA (16x16x32), fp32 softmax/accum, causal, GQA R=4.
// grid = (T/64, H, B), 256 threads (4 waves). Wave w owns q rows [w*16, w*16+16)
// of a 64-row q tile. K/V read directly from global (L2-resident).
// P re-layout via wave-private XOR-swizzled LDS.
// MFMA layouts (verified, learn_hip m89/m91):
//   A-frag: row = lane&15, k = (lane>>4)*8 + i (contiguous 8 bf16)
//   B-frag: col = lane&15, k = (lane>>4)*8 + i
//   C/D:    col = lane&15, row = (lane>>4)*4 + reg
// ---------------------------------------------------------------------------
__global__ __launch_bounds__(256)
void attn_mfma(const __hip_bfloat16* __restrict__ Qb,
               const __hip_bfloat16* __restrict__ Kb,
               const __hip_bfloat16* __restrict__ VTb,
               float* __restrict__ Ob)
{
    __shared__ __hip_bfloat16 P_lds[4][16 * 64];
    const int qt = (int)gridDim.x - 1 - (int)blockIdx.x;   // heavy tiles first
    const int h = blockIdx.y, b = blockIdx.z;
    const int kvh = h >> 2;
    const int tid = threadIdx.x;
    const int w = tid >> 6, lane = tid & 63;
    const int l15 = lane & 15, g = lane >> 4;

    const __hip_bfloat16* Qh = Qb + (((size_t)b * H_ + h) * T_ + qt * 64 + w * 16) * 64;
    const __hip_bfloat16* Kh = Kb + (((size_t)b * KV_ + kvh) * T_) * 64;
    const __hip_bfloat16* Vh = VTb + ((size_t)b * KV_ + kvh) * 64 * (size_t)T_;

    short8 qf[2];
    qf[0] = *reinterpret_cast<const short8*>(Qh + l15 * 64 + g * 8);
    qf[1] = *reinterpret_cast<const short8*>(Qh + l15 * 64 + 32 + g * 8);

    f32x4 o4[4] = {};
    float m_[4] = {-INFINITY, -INFINITY, -INFINITY, -INFINITY};
    float l_[4] = {0.f, 0.f, 0.f, 0.f};
    __hip_bfloat16* Pw = P_lds[w];

    for (int j = 0; j <= qt; ++j) {
        const __hip_bfloat16* Kt = Kh + (size_t)(j * 64) * 64;
        f32x4 s4[4] = {};
#pragma unroll
        for (int kk = 0; kk < 2; ++kk) {
#pragma unroll
            for (int n = 0; n < 4; ++n) {
                short8 kf = *reinterpret_cast<const short8*>(Kt + (n * 16 + l15) * 64 + kk * 32 + g * 8);
                s4[n] = __builtin_amdgcn_mfma_f32_16x16x32_bf16(qf[kk], kf, s4[n], 0, 0, 0);
            }
        }
        // scale (+ causal mask on the diagonal tile)
        const int rowq = qt * 64 + w * 16 + g * 4;
        const bool diag = (j == qt);
#pragma unroll
        for (int n = 0; n < 4; ++n) {
            const int col = j * 64 + n * 16 + l15;
#pragma unroll
            for (int r = 0; r < 4; ++r) {
                float sv = s4[n][r] * 0.125f;
                if (diag && col > rowq + r) sv = -1e30f;
                s4[n][r] = sv;
            }
        }
        // online softmax, rows live in (16-lane-group, reg) space
#pragma unroll
        for (int r = 0; r < 4; ++r) {
            float tmax = fmaxf(fmaxf(s4[0][r], s4[1][r]), fmaxf(s4[2][r], s4[3][r]));
            tmax = fmaxf(tmax, __shfl_xor(tmax, 1));
            tmax = fmaxf(tmax, __shfl_xor(tmax, 2));
            tmax = fmaxf(tmax, __shfl_xor(tmax, 4));
            tmax = fmaxf(tmax, __shfl_xor(tmax, 8));
            const float mn = fmaxf(m_[r], tmax);
            const float sc = __expf(m_[r] - mn);
            float ps = 0.f;
#pragma unroll
            for (int n = 0; n < 4; ++n) {
                float p = __expf(s4[n][r] - mn);
                s4[n][r] = p;
                ps += p;
            }
            ps += __shfl_xor(ps, 1);
            ps += __shfl_xor(ps, 2);
            ps += __shfl_xor(ps, 4);
            ps += __shfl_xor(ps, 8);
            l_[r] = l_[r] * sc + ps;
            m_[r] = mn;
#pragma unroll
            for (int n = 0; n < 4; ++n) o4[n][r] *= sc;
        }
        // P (fp32, D-layout) -> bf16 -> swizzled wave-private LDS
#pragma unroll
        for (int n = 0; n < 4; ++n) {
#pragma unroll
            for (int r = 0; r < 4; ++r) {
                const int row = g * 4 + r;
                const int col = n * 16 + l15;
                Pw[row * 64 + (col ^ ((row & 7) << 3))] = __float2bfloat16(s4[n][r]);
            }
        }
        // PV: A-frag = P row (swizzled LDS read), B-frag = V^T (contiguous global)
#pragma unroll
        for (int kk = 0; kk < 2; ++kk) {
            const int row = l15;
            const int c0 = kk * 32 + g * 8;
            short8 pf = *reinterpret_cast<const short8*>(Pw + row * 64 + (c0 ^ ((row & 7) << 3)));
#pragma unroll
            for (int n = 0; n < 4; ++n) {
                short8 vf = *reinterpret_cast<const short8*>(
                    Vh + (size_t)(n * 16 + l15) * T_ + j * 64 + kk * 32 + g * 8);
                o4[n] = __builtin_amdgcn_mfma_f32_16x16x32_bf16(pf, vf, o4[n], 0, 0, 0);
            }
        }
    }

    // epilogue: O[b][t][h][d] fp32 (rows of the (B*T) x 2048 matrix for the out-proj)
#pragma unroll
    for (int r = 0; r < 4; ++r) {
        const float inv = 1.f / l_[r];
        const int qg = qt * 64 + w * 16 + g * 4 + r;
        float* op = Ob + ((size_t)b * T_ + qg) * QW + h * 64;
#pragma unroll
        for (int n = 0; n < 4; ++n)
            op[n * 16 + l15] = o4[n][r] * inv;
    }
}

// ---------------------------------------------------------------------------
// Launch. Workspace layout (104 MB):
//   Q f32 4096x2048 @ 0        (32 MB)
//   K f32 4096x512  @ 32 MB    ( 8 MB)
//   V f32 4096x512  @ 40 MB    ( 8 MB)
//   O f32 4096x2048 @ 48 MB    (32 MB)
//   Qbf   [b][h][t][64]  @ 80 MB  (16 MB)
//   Kbf   [b][kv][t][64] @ 96 MB  ( 4 MB)
//   VT    [b][kv][64][t] @ 100 MB ( 4 MB)
// ---------------------------------------------------------------------------
extern "C" void kernel_launch(void* const* d_in, const int* in_sizes, int n_in,
                              void* d_out, int out_size, void* d_ws, size_t ws_size,
                              hipStream_t stream)
{
    const float* x  = (const float*)d_in[0];
    const float* fc = (const float*)d_in[1];
    const float* Wq = (const float*)d_in[2];
    const float* Wk = (const float*)d_in[3];
    const float* Wv = (const float*)d_in[4];
    const float* Wo = (const float*)d_in[5];
    float* out = (float*)d_out;

    char* ws = (char*)d_ws;
    float* Q  = (float*)(ws);
    float* K  = (float*)(ws + 33554432);
    float* V  = (float*)(ws + 41943040);
    float* O  = (float*)(ws + 50331648);
    __hip_bfloat16* Qbf = (__hip_bfloat16*)(ws + 83886080);
    __hip_bfloat16* Kbf = (__hip_bfloat16*)(ws + 100663296);
    __hip_bfloat16* VT  = (__hip_bfloat16*)(ws + 104857600);

    // 1) QKV projections (fp32): x(4096x2048) @ {Wq,Wk,Wv}
    gemm_qkv<<<dim3(24, 32), 256, 0, stream>>>(x, Wq, Wk, Wv, Q, K, V);

    // 2) RoPE + bf16 cast + head-major re-layout; V transpose-cast
    prep_qk<<<TPAIRS / 256, 256, 0, stream>>>(Q, K, fc, Qbf, Kbf);
    transpose_v<<<dim3(T_ / 64, B_ * KV_), 256, 0, stream>>>(V, VT);

    // 3) Causal GQA flash attention (bf16 MFMA) -> O (B,T,H,D) fp32
    attn_mfma<<<dim3(T_ / 64, H_, B_), 256, 0, stream>>>(Qbf, Kbf, VT, O);

    // 4) Output projection (fp32): O @ Wo -> out
    gemm128<<<dim3(QW / BN, NROW / BM), 256, 0, stream>>>(O, Wo, out, E_, E_);
}

// Round 4
// 764.588 us; speedup vs baseline: 8.4955x; 2.1027x over previous
//
#include <hip/hip_runtime.h>
#include <hip/hip_bf16.h>
#include <math.h>

// Problem constants (GroupedQueryAttention: B=2,T=2048,E=2048,H=32,KV=8,D=64,R=4)
#define B_   2
#define T_   2048
#define E_   2048
#define H_   32
#define KV_  8
#define D_   64
#define NROW (B_*T_)          // 4096 rows of x
#define QW   (H_*D_)          // 2048
#define KW   (KV_*D_)         // 512
#define NQKV 3072             // fused [Q|K|V] projection width

typedef __attribute__((ext_vector_type(8))) short short8;
typedef __attribute__((ext_vector_type(4))) float f32x4;

__device__ __forceinline__ ushort f2bf(float f) {
    __hip_bfloat16 h = __float2bfloat16(f);
    return *reinterpret_cast<ushort*>(&h);
}
__device__ __forceinline__ float bf2f(ushort u) {
    union { unsigned int i; float f; } v; v.i = ((unsigned int)u) << 16; return v.f;
}

// async global->LDS, 16B per lane. LDS dest must be wave-uniform base (+lane*16).
__device__ __forceinline__ void gload_lds16(const ushort* g, ushort* l) {
    __builtin_amdgcn_global_load_lds(
        (const __attribute__((address_space(1))) void*)g,
        (__attribute__((address_space(3))) void*)l,
        16, 0, 0);
}

// ---------------------------------------------------------------------------
// cast_bf16: fp32 -> bf16, 8 elems/thread (32B in / 16B out per lane)
// ---------------------------------------------------------------------------
__global__ __launch_bounds__(256)
void cast_bf16(const float* __restrict__ src, ushort* __restrict__ dst)
{
    const size_t i = ((size_t)blockIdx.x * 256 + threadIdx.x) * 8;
    float4 v0 = *reinterpret_cast<const float4*>(src + i);
    float4 v1 = *reinterpret_cast<const float4*>(src + i + 4);
    ushort o[8] = {f2bf(v0.x), f2bf(v0.y), f2bf(v0.z), f2bf(v0.w),
                   f2bf(v1.x), f2bf(v1.y), f2bf(v1.z), f2bf(v1.w)};
    *reinterpret_cast<short8*>(dst + i) = *reinterpret_cast<const short8*>(o);
}

// ---------------------------------------------------------------------------
// transcast: src fp32 [R][C] row-major -> dst bf16 [C][R] (weight transpose).
// 64x64 LDS tiles, conflict-free ([64][65] padding).
// grid = (C/64, R/64). dst may be a row-offset slice; dst row stride = R.
// ---------------------------------------------------------------------------
__global__ __launch_bounds__(256)
void transcast(const float* __restrict__ src, ushort* __restrict__ dst, int R, int C)
{
    __shared__ float tile[64][65];
    const int r0 = blockIdx.y * 64, c0 = blockIdx.x * 64;
    const int tid = threadIdx.x;
    const int cc = tid & 63, rb = tid >> 6;
#pragma unroll
    for (int i = 0; i < 16; ++i) {
        int r = rb + i * 4;
        tile[r][cc] = src[(size_t)(r0 + r) * C + c0 + cc];
    }
    __syncthreads();
#pragma unroll
    for (int i = 0; i < 16; ++i) {
        int rr = rb + i * 4;   // dst row within tile (= src col)
        dst[(size_t)(c0 + rr) * R + r0 + cc] = f2bf(tile[cc][rr]);
    }
}

// ---------------------------------------------------------------------------
// gemm_bt: C[M x N] = A[M x K](bf16) * BT[N x K](bf16)^T, fp32 accum.
// m97 structure: 128x128 tile, BK=32, 4 waves (2x2), each wave 64x64 out
// (4x4 fragments of 16x16x32 MFMA). global_load_lds width-16 staging,
// 2 barriers per K-step. Output fp32 or bf16.
// MFMA layouts (verified): A/B-frag: row/col = lane&15, k = (lane>>4)*8+i;
// C/D: col = lane&15, row = (lane>>4)*4 + reg.
// ---------------------------------------------------------------------------
template<bool BF16OUT>
__global__ __launch_bounds__(256)
void gemm_bt(const ushort* __restrict__ A, const ushort* __restrict__ BT,
             void* __restrict__ Cv, int N, int K)
{
    __shared__ __align__(16) ushort As[128 * 32];
    __shared__ __align__(16) ushort Bs[128 * 32];
    const int tid = threadIdx.x;
    const int w = tid >> 6, lane = tid & 63;
    const int l15 = lane & 15, g = lane >> 4;
    const int wr = w >> 1, wc = w & 1;
    const size_t brow = (size_t)blockIdx.y * 128, bcol = (size_t)blockIdx.x * 128;

    f32x4 acc[4][4] = {};

    // staging: wave w owns tile rows [w*32, w*32+32), as two 16-row/1KB chunks.
    const int srow = w * 32 + (lane >> 2);     // chunk-0 row for this lane
    const int skc  = (lane & 3) * 8;           // k offset (ushort) within row
    const ushort* gA = A  + (brow + srow) * K + skc;
    const ushort* gB = BT + (bcol + srow) * K + skc;
    ushort* lA = &As[(w * 32) * 32];           // wave-uniform LDS bases
    ushort* lB = &Bs[(w * 32) * 32];

    for (int k0 = 0; k0 < K; k0 += 32) {
        gload_lds16(gA + k0,                  lA);
        gload_lds16(gA + k0 + (size_t)16 * K, lA + 16 * 32);
        gload_lds16(gB + k0,                  lB);
        gload_lds16(gB + k0 + (size_t)16 * K, lB + 16 * 32);
        __syncthreads();   // drains vmcnt before ds_read

        short8 a[4], b[4];
#pragma unroll
        for (int m = 0; m < 4; ++m)
            a[m] = *reinterpret_cast<const short8*>(&As[(wr * 64 + m * 16 + l15) * 32 + g * 8]);
#pragma unroll
        for (int n = 0; n < 4; ++n)
            b[n] = *reinterpret_cast<const short8*>(&Bs[(wc * 64 + n * 16 + l15) * 32 + g * 8]);
#pragma unroll
        for (int m = 0; m < 4; ++m)
#pragma unroll
            for (int n = 0; n < 4; ++n)
                acc[m][n] = __builtin_amdgcn_mfma_f32_16x16x32_bf16(a[m], b[n], acc[m][n], 0, 0, 0);
        __syncthreads();   // protect LDS before next stage
    }

#pragma unroll
    for (int m = 0; m < 4; ++m) {
#pragma unroll
        for (int r = 0; r < 4; ++r) {
            const size_t row = brow + wr * 64 + m * 16 + g * 4 + r;
#pragma unroll
            for (int n = 0; n < 4; ++n) {
                const size_t col = bcol + wc * 64 + n * 16 + l15;
                if (BF16OUT) ((ushort*)Cv)[row * N + col] = f2bf(acc[m][n][r]);
                else         ((float*) Cv)[row * N + col] = acc[m][n][r];
            }
        }
    }
}

// ---------------------------------------------------------------------------
// prep_qk: RoPE on bf16 QKV slab + re-layout head-major bf16.
//   Qb: [b][h][t][64]   Kb: [b][kvh][t][64]
// ---------------------------------------------------------------------------
#define QPAIRS (NROW * H_  * 32)   // 4,194,304
#define KPAIRS (NROW * KV_ * 32)   // 1,048,576
#define TPAIRS (QPAIRS + KPAIRS)   // 5,242,880

__global__ __launch_bounds__(256)
void prep_qk(const ushort* __restrict__ QKVb, const float* __restrict__ fc,
             ushort* __restrict__ Qb, ushort* __restrict__ Kb)
{
    int idx = blockIdx.x * 256 + threadIdx.x;
    if (idx < QPAIRS) {
        // idx = ((b*H + h)*T + t)*32 + p
        int p = idx & 31;
        int t = (idx >> 5) & (T_ - 1);
        int bh = idx >> 16;
        int h = bh & (H_ - 1), b = bh >> 5;
        ushort2 ab = *reinterpret_cast<const ushort2*>(
            QKVb + (size_t)(b * T_ + t) * NQKV + h * 64 + p * 2);
        float c = fc[t * 64 + p * 2], s = fc[t * 64 + p * 2 + 1];
        float x0 = bf2f(ab.x), x1 = bf2f(ab.y);
        ushort2 pk;
        pk.x = f2bf(x0 * c - x1 * s);
        pk.y = f2bf(x0 * s + x1 * c);
        *reinterpret_cast<ushort2*>(Qb + (size_t)idx * 2) = pk;
    } else {
        int i2 = idx - QPAIRS;              // ((b*KV + kh)*T + t)*32 + p
        int p = i2 & 31;
        int t = (i2 >> 5) & (T_ - 1);
        int bk = i2 >> 16;
        int kh = bk & 7, b = bk >> 3;
        ushort2 ab = *reinterpret_cast<const ushort2*>(
            QKVb + (size_t)(b * T_ + t) * NQKV + 2048 + kh * 64 + p * 2);
        float c = fc[t * 64 + p * 2], s = fc[t * 64 + p * 2 + 1];
        float x0 = bf2f(ab.x), x1 = bf2f(ab.y);
        ushort2 pk;
        pk.x = f2bf(x0 * c - x1 * s);
        pk.y = f2bf(x0 * s + x1 * c);
        *reinterpret_cast<ushort2*>(Kb + (size_t)i2 * 2) = pk;
    }
}

// ---------------------------------------------------------------------------
// transpose_v: QKV V-slice bf16 [b t][kvh d] -> VT bf16 [b][kvh][d][t]
// ---------------------------------------------------------------------------
__global__ __launch_bounds__(256)
void transpose_v(const ushort* __restrict__ QKVb, ushort* __restrict__ VT)
{
    __shared__ ushort tile[64][65];
    const int t0 = blockIdx.x * 64;
    const int bk = blockIdx.y;              // b*KV + kvh
    const int b = bk >> 3, kh = bk & 7;
    const int tid = threadIdx.x;
    const int c = tid & 63, rbase = tid >> 6;
#pragma unroll
    for (int i = 0; i < 16; ++i) {
        int r = rbase + i * 4;
        tile[r][c] = QKVb[(size_t)(b * T_ + t0 + r) * NQKV + 2560 + kh * 64 + c];
    }
    __syncthreads();
#pragma unroll
    for (int i = 0; i < 16; ++i) {
        int d = rbase + i * 4;
        VT[((size_t)bk * 64 + d) * T_ + t0 + c] = tile[c][d];
    }
}

// ---------------------------------------------------------------------------
// Flash attention, bf16 MFMA (16x16x32), fp32 softmax/accum, causal, GQA R=4.
// grid = (T/64, H, B), 256 threads (4 waves); wave w owns 16 q-rows.
// Output is bf16 head-major [B*T][H*D].
// ---------------------------------------------------------------------------
__global__ __launch_bounds__(256)
void attn_mfma(const ushort* __restrict__ Qb,
               const ushort* __restrict__ Kb,
               const ushort* __restrict__ VTb,
               ushort* __restrict__ Ob)
{
    __shared__ __align__(16) ushort P_lds[4][16 * 64];
    const int qt = (int)gridDim.x - 1 - (int)blockIdx.x;   // heavy tiles first
    const int h = blockIdx.y, b = blockIdx.z;
    const int kvh = h >> 2;
    const int tid = threadIdx.x;
    const int w = tid >> 6, lane = tid & 63;
    const int l15 = lane & 15, g = lane >> 4;

    const ushort* Qh = Qb + (((size_t)b * H_ + h) * T_ + qt * 64 + w * 16) * 64;
    const ushort* Kh = Kb + (((size_t)b * KV_ + kvh) * T_) * 64;
    const ushort* Vh = VTb + ((size_t)b * KV_ + kvh) * 64 * (size_t)T_;

    short8 qf[2];
    qf[0] = *reinterpret_cast<const short8*>(Qh + l15 * 64 + g * 8);
    qf[1] = *reinterpret_cast<const short8*>(Qh + l15 * 64 + 32 + g * 8);

    f32x4 o4[4] = {};
    float m_[4] = {-INFINITY, -INFINITY, -INFINITY, -INFINITY};
    float l_[4] = {0.f, 0.f, 0.f, 0.f};
    ushort* Pw = P_lds[w];

    for (int j = 0; j <= qt; ++j) {
        const ushort* Kt = Kh + (size_t)(j * 64) * 64;
        f32x4 s4[4] = {};
#pragma unroll
        for (int kk = 0; kk < 2; ++kk) {
#pragma unroll
            for (int n = 0; n < 4; ++n) {
                short8 kf = *reinterpret_cast<const short8*>(Kt + (n * 16 + l15) * 64 + kk * 32 + g * 8);
                s4[n] = __builtin_amdgcn_mfma_f32_16x16x32_bf16(qf[kk], kf, s4[n], 0, 0, 0);
            }
        }
        const int rowq = qt * 64 + w * 16 + g * 4;
        const bool diag = (j == qt);
#pragma unroll
        for (int n = 0; n < 4; ++n) {
            const int col = j * 64 + n * 16 + l15;
#pragma unroll
            for (int r = 0; r < 4; ++r) {
                float sv = s4[n][r] * 0.125f;
                if (diag && col > rowq + r) sv = -1e30f;
                s4[n][r] = sv;
            }
        }
#pragma unroll
        for (int r = 0; r < 4; ++r) {
            float tmax = fmaxf(fmaxf(s4[0][r], s4[1][r]), fmaxf(s4[2][r], s4[3][r]));
            tmax = fmaxf(tmax, __shfl_xor(tmax, 1));
            tmax = fmaxf(tmax, __shfl_xor(tmax, 2));
            tmax = fmaxf(tmax, __shfl_xor(tmax, 4));
            tmax = fmaxf(tmax, __shfl_xor(tmax, 8));
            const float mn = fmaxf(m_[r], tmax);
            const float sc = __expf(m_[r] - mn);
            float ps = 0.f;
#pragma unroll
            for (int n = 0; n < 4; ++n) {
                float p = __expf(s4[n][r] - mn);
                s4[n][r] = p;
                ps += p;
            }
            ps += __shfl_xor(ps, 1);
            ps += __shfl_xor(ps, 2);
            ps += __shfl_xor(ps, 4);
            ps += __shfl_xor(ps, 8);
            l_[r] = l_[r] * sc + ps;
            m_[r] = mn;
#pragma unroll
            for (int n = 0; n < 4; ++n) o4[n][r] *= sc;
        }
        // P (fp32, D-layout) -> bf16 -> swizzled wave-private LDS
#pragma unroll
        for (int n = 0; n < 4; ++n) {
#pragma unroll
            for (int r = 0; r < 4; ++r) {
                const int row = g * 4 + r;
                const int col = n * 16 + l15;
                Pw[row * 64 + (col ^ ((row & 7) << 3))] = f2bf(s4[n][r]);
            }
        }
        // PV: A-frag = P row (swizzled LDS read), B-frag = V^T (contiguous global)
#pragma unroll
        for (int kk = 0; kk < 2; ++kk) {
            const int row = l15;
            const int c0 = kk * 32 + g * 8;
            short8 pf = *reinterpret_cast<const short8*>(Pw + row * 64 + (c0 ^ ((row & 7) << 3)));
#pragma unroll
            for (int n = 0; n < 4; ++n) {
                short8 vf = *reinterpret_cast<const short8*>(
                    Vh + (size_t)(n * 16 + l15) * T_ + j * 64 + kk * 32 + g * 8);
                o4[n] = __builtin_amdgcn_mfma_f32_16x16x32_bf16(pf, vf, o4[n], 0, 0, 0);
            }
        }
    }

    // epilogue: O[b][t][h][d] bf16 (rows of the (B*T) x 2048 out-proj input)
#pragma unroll
    for (int r = 0; r < 4; ++r) {
        const float inv = 1.f / l_[r];
        const int qg = qt * 64 + w * 16 + g * 4 + r;
        ushort* op = Ob + ((size_t)b * T_ + qg) * QW + h * 64;
#pragma unroll
        for (int n = 0; n < 4; ++n)
            op[n * 16 + l15] = f2bf(o4[n][r] * inv);
    }
}

// ---------------------------------------------------------------------------
// Workspace layout (84 MB high-water):
//   xb / Obf bf16 [4096][2048] @ 0         (16 MB)  (Obf reuses xb after gemm1)
//   WT   bf16 [3072][2048]     @ 16777216  (12 MB)  ([Wq|Wk|Wv]^T)
//   WTo  bf16 [2048][2048]     @ 29360128  ( 8 MB)
//   QKVb bf16 [4096][3072]     @ 37748736  (24 MB)
//   Qbf  bf16 [b][h][t][64]    @ 62914560  (16 MB)
//   Kbf  bf16 [b][kv][t][64]   @ 79691776  ( 4 MB)
//   VT   bf16 [b][kv][64][t]   @ 83886080  ( 4 MB)
// ---------------------------------------------------------------------------
extern "C" void kernel_launch(void* const* d_in, const int* in_sizes, int n_in,
                              void* d_out, int out_size, void* d_ws, size_t ws_size,
                              hipStream_t stream)
{
    const float* x  = (const float*)d_in[0];
    const float* fc = (const float*)d_in[1];
    const float* Wq = (const float*)d_in[2];
    const float* Wk = (const float*)d_in[3];
    const float* Wv = (const float*)d_in[4];
    const float* Wo = (const float*)d_in[5];
    float* out = (float*)d_out;

    char* ws = (char*)d_ws;
    ushort* xb   = (ushort*)(ws);
    ushort* WT   = (ushort*)(ws + 16777216);
    ushort* WTo  = (ushort*)(ws + 29360128);
    ushort* QKVb = (ushort*)(ws + 37748736);
    ushort* Qbf  = (ushort*)(ws + 62914560);
    ushort* Kbf  = (ushort*)(ws + 79691776);
    ushort* VT   = (ushort*)(ws + 83886080);
    ushort* Obf  = xb;   // xb dead after QKV gemm

    // 1) casts + weight transposes (bf16)
    cast_bf16<<<4096, 256, 0, stream>>>(x, xb);
    transcast<<<dim3(32, 32), 256, 0, stream>>>(Wq, WT, E_, QW);
    transcast<<<dim3( 8, 32), 256, 0, stream>>>(Wk, WT + (size_t)2048 * 2048, E_, KW);
    transcast<<<dim3( 8, 32), 256, 0, stream>>>(Wv, WT + (size_t)2560 * 2048, E_, KW);
    transcast<<<dim3(32, 32), 256, 0, stream>>>(Wo, WTo, QW, E_);

    // 2) fused QKV projection (bf16 MFMA): xb @ WT^T -> QKVb [4096][3072]
    gemm_bt<true><<<dim3(NQKV / 128, NROW / 128), 256, 0, stream>>>(xb, WT, QKVb, NQKV, E_);

    // 3) RoPE + head-major re-layout; V transpose
    prep_qk<<<TPAIRS / 256, 256, 0, stream>>>(QKVb, fc, Qbf, Kbf);
    transpose_v<<<dim3(T_ / 64, B_ * KV_), 256, 0, stream>>>(QKVb, VT);

    // 4) causal GQA flash attention (bf16 MFMA) -> Obf bf16 [4096][2048]
    attn_mfma<<<dim3(T_ / 64, H_, B_), 256, 0, stream>>>(Qbf, Kbf, VT, Obf);

    // 5) output projection (bf16 MFMA, fp32 out): Obf @ WTo^T -> out
    gemm_bt<false><<<dim3(E_ / 128, NROW / 128), 256, 0, stream>>>(Obf, WTo, out, E_, E_);
}

// Round 5
// 471.770 us; speedup vs baseline: 13.7685x; 1.6207x over previous
//
#include <hip/hip_runtime.h>
#include <hip/hip_bf16.h>
#include <math.h>

// Problem constants (GroupedQueryAttention: B=2,T=2048,E=2048,H=32,KV=8,D=64,R=4)
#define B_   2
#define T_   2048
#define E_   2048
#define H_   32
#define KV_  8
#define D_   64
#define NROW (B_*T_)          // 4096 rows of x
#define QW   (H_*D_)          // 2048
#define KW   (KV_*D_)         // 512
#define NQKV 3072             // fused [Q|K|V] projection width

typedef __attribute__((ext_vector_type(8))) short short8;
typedef __attribute__((ext_vector_type(4))) float f32x4;

__device__ __forceinline__ ushort f2bf(float f) {
    __hip_bfloat16 h = __float2bfloat16(f);
    return *reinterpret_cast<ushort*>(&h);
}
__device__ __forceinline__ float bf2f(ushort u) {
    union { unsigned int i; float f; } v; v.i = ((unsigned int)u) << 16; return v.f;
}

// async global->LDS, 16B per lane. LDS dest must be wave-uniform base (+lane*16).
__device__ __forceinline__ void gload_lds16(const ushort* g, ushort* l) {
    __builtin_amdgcn_global_load_lds(
        (const __attribute__((address_space(1))) void*)g,
        (__attribute__((address_space(3))) void*)l,
        16, 0, 0);
}

// ---------------------------------------------------------------------------
// cast_bf16: fp32 -> bf16, 8 elems/thread
// ---------------------------------------------------------------------------
__global__ __launch_bounds__(256)
void cast_bf16(const float* __restrict__ src, ushort* __restrict__ dst)
{
    const size_t i = ((size_t)blockIdx.x * 256 + threadIdx.x) * 8;
    float4 v0 = *reinterpret_cast<const float4*>(src + i);
    float4 v1 = *reinterpret_cast<const float4*>(src + i + 4);
    ushort o[8] = {f2bf(v0.x), f2bf(v0.y), f2bf(v0.z), f2bf(v0.w),
                   f2bf(v1.x), f2bf(v1.y), f2bf(v1.z), f2bf(v1.w)};
    *reinterpret_cast<short8*>(dst + i) = *reinterpret_cast<const short8*>(o);
}

// ---------------------------------------------------------------------------
// transcast: src fp32 [R][C] row-major -> dst bf16 [C][R] (weight transpose).
// ---------------------------------------------------------------------------
__global__ __launch_bounds__(256)
void transcast(const float* __restrict__ src, ushort* __restrict__ dst, int R, int C)
{
    __shared__ float tile[64][65];
    const int r0 = blockIdx.y * 64, c0 = blockIdx.x * 64;
    const int tid = threadIdx.x;
    const int cc = tid & 63, rb = tid >> 6;
#pragma unroll
    for (int i = 0; i < 16; ++i) {
        int r = rb + i * 4;
        tile[r][cc] = src[(size_t)(r0 + r) * C + c0 + cc];
    }
    __syncthreads();
#pragma unroll
    for (int i = 0; i < 16; ++i) {
        int rr = rb + i * 4;
        dst[(size_t)(c0 + rr) * R + r0 + cc] = f2bf(tile[cc][rr]);
    }
}

// ---------------------------------------------------------------------------
// gemm_bt: C[M x N] = A[M x K](bf16) * BT[N x K](bf16)^T, fp32 accum.
// m97 structure (unchanged from round 4).
// ---------------------------------------------------------------------------
template<bool BF16OUT>
__global__ __launch_bounds__(256)
void gemm_bt(const ushort* __restrict__ A, const ushort* __restrict__ BT,
             void* __restrict__ Cv, int N, int K)
{
    __shared__ __align__(16) ushort As[128 * 32];
    __shared__ __align__(16) ushort Bs[128 * 32];
    const int tid = threadIdx.x;
    const int w = tid >> 6, lane = tid & 63;
    const int l15 = lane & 15, g = lane >> 4;
    const int wr = w >> 1, wc = w & 1;
    const size_t brow = (size_t)blockIdx.y * 128, bcol = (size_t)blockIdx.x * 128;

    f32x4 acc[4][4] = {};

    const int srow = w * 32 + (lane >> 2);
    const int skc  = (lane & 3) * 8;
    const ushort* gA = A  + (brow + srow) * K + skc;
    const ushort* gB = BT + (bcol + srow) * K + skc;
    ushort* lA = &As[(w * 32) * 32];
    ushort* lB = &Bs[(w * 32) * 32];

    for (int k0 = 0; k0 < K; k0 += 32) {
        gload_lds16(gA + k0,                  lA);
        gload_lds16(gA + k0 + (size_t)16 * K, lA + 16 * 32);
        gload_lds16(gB + k0,                  lB);
        gload_lds16(gB + k0 + (size_t)16 * K, lB + 16 * 32);
        __syncthreads();

        short8 a[4], b[4];
#pragma unroll
        for (int m = 0; m < 4; ++m)
            a[m] = *reinterpret_cast<const short8*>(&As[(wr * 64 + m * 16 + l15) * 32 + g * 8]);
#pragma unroll
        for (int n = 0; n < 4; ++n)
            b[n] = *reinterpret_cast<const short8*>(&Bs[(wc * 64 + n * 16 + l15) * 32 + g * 8]);
#pragma unroll
        for (int m = 0; m < 4; ++m)
#pragma unroll
            for (int n = 0; n < 4; ++n)
                acc[m][n] = __builtin_amdgcn_mfma_f32_16x16x32_bf16(a[m], b[n], acc[m][n], 0, 0, 0);
        __syncthreads();
    }

#pragma unroll
    for (int m = 0; m < 4; ++m) {
#pragma unroll
        for (int r = 0; r < 4; ++r) {
            const size_t row = brow + wr * 64 + m * 16 + g * 4 + r;
#pragma unroll
            for (int n = 0; n < 4; ++n) {
                const size_t col = bcol + wc * 64 + n * 16 + l15;
                if (BF16OUT) ((ushort*)Cv)[row * N + col] = f2bf(acc[m][n][r]);
                else         ((float*) Cv)[row * N + col] = acc[m][n][r];
            }
        }
    }
}

// ---------------------------------------------------------------------------
// prep_qk: RoPE on bf16 QKV slab + head-major re-layout.
// Q additionally pre-scaled by 1/sqrt(D)=0.125 (exact in bf16: exponent shift).
// ---------------------------------------------------------------------------
#define QPAIRS (NROW * H_  * 32)   // 4,194,304
#define KPAIRS (NROW * KV_ * 32)   // 1,048,576
#define TPAIRS (QPAIRS + KPAIRS)   // 5,242,880

__global__ __launch_bounds__(256)
void prep_qk(const ushort* __restrict__ QKVb, const float* __restrict__ fc,
             ushort* __restrict__ Qb, ushort* __restrict__ Kb)
{
    int idx = blockIdx.x * 256 + threadIdx.x;
    if (idx < QPAIRS) {
        int p = idx & 31;
        int t = (idx >> 5) & (T_ - 1);
        int bh = idx >> 16;
        int h = bh & (H_ - 1), b = bh >> 5;
        ushort2 ab = *reinterpret_cast<const ushort2*>(
            QKVb + (size_t)(b * T_ + t) * NQKV + h * 64 + p * 2);
        float c = fc[t * 64 + p * 2], s = fc[t * 64 + p * 2 + 1];
        float x0 = bf2f(ab.x), x1 = bf2f(ab.y);
        ushort2 pk;
        pk.x = f2bf((x0 * c - x1 * s) * 0.125f);
        pk.y = f2bf((x0 * s + x1 * c) * 0.125f);
        *reinterpret_cast<ushort2*>(Qb + (size_t)idx * 2) = pk;
    } else {
        int i2 = idx - QPAIRS;
        int p = i2 & 31;
        int t = (i2 >> 5) & (T_ - 1);
        int bk = i2 >> 16;
        int kh = bk & 7, b = bk >> 3;
        ushort2 ab = *reinterpret_cast<const ushort2*>(
            QKVb + (size_t)(b * T_ + t) * NQKV + 2048 + kh * 64 + p * 2);
        float c = fc[t * 64 + p * 2], s = fc[t * 64 + p * 2 + 1];
        float x0 = bf2f(ab.x), x1 = bf2f(ab.y);
        ushort2 pk;
        pk.x = f2bf(x0 * c - x1 * s);
        pk.y = f2bf(x0 * s + x1 * c);
        *reinterpret_cast<ushort2*>(Kb + (size_t)i2 * 2) = pk;
    }
}

// ---------------------------------------------------------------------------
// transpose_v: QKV V-slice bf16 [b t][kvh d] -> VT bf16 [b][kvh][d][t]
// ---------------------------------------------------------------------------
__global__ __launch_bounds__(256)
void transpose_v(const ushort* __restrict__ QKVb, ushort* __restrict__ VT)
{
    __shared__ ushort tile[64][65];
    const int t0 = blockIdx.x * 64;
    const int bk = blockIdx.y;
    const int b = bk >> 3, kh = bk & 7;
    const int tid = threadIdx.x;
    const int c = tid & 63, rbase = tid >> 6;
#pragma unroll
    for (int i = 0; i < 16; ++i) {
        int r = rbase + i * 4;
        tile[r][c] = QKVb[(size_t)(b * T_ + t0 + r) * NQKV + 2560 + kh * 64 + c];
    }
    __syncthreads();
#pragma unroll
    for (int i = 0; i < 16; ++i) {
        int d = rbase + i * 4;
        VT[((size_t)bk * 64 + d) * T_ + t0 + c] = tile[c][d];
    }
}

// ---------------------------------------------------------------------------
// Flash attention v2: bf16 MFMA, fp32 softmax, causal, GQA R=4.
// grid = (T/128, H, B), 256 threads (4 waves). Block owns 128 q-rows;
// wave w owns rows [w*32, w*32+32) as two 16-row fragment sets.
// K/V tiles (64 kv x 64 d) staged cooperatively in double-buffered,
// XOR-swizzled LDS via global_load_lds (rule #21: linear dest +
// inverse-swizzled global source + swizzled read). One barrier per tile;
// next tile's stage issued before current tile's compute (2-phase overlap).
//
// Swizzle: row of 64 ushort = 8 chunks of 16B; data chunk c of row r lives
// at physical chunk c ^ (r&7). Spreads the 16-rows-same-column ds_read
// pattern from 16-way conflict to <=2-way (free).
// ---------------------------------------------------------------------------
__device__ __forceinline__
void stage_kv(const ushort* __restrict__ Kh, const ushort* __restrict__ Vh,
              ushort* lK, ushort* lV, int j, int w, int lane)
{
    const int rsub = lane >> 3;          // 0..7: row within 8-row group
    const int sc   = (lane & 7) ^ rsub;  // inverse-swizzled source chunk
#pragma unroll
    for (int it = 0; it < 2; ++it) {
        const int row = w * 16 + it * 8 + rsub;          // 0..63
        // K: [t][d] rows, row stride 64
        gload_lds16(Kh + ((size_t)(j * 64 + row)) * 64 + sc * 8,
                    lK + (w * 16 + it * 8) * 64);
        // V^T: [d][t] rows, row stride T_
        gload_lds16(Vh + (size_t)row * T_ + j * 64 + sc * 8,
                    lV + (w * 16 + it * 8) * 64);
    }
}

#define AQB 128   // q rows per attention block

__global__ __launch_bounds__(256)
void attn_mfma2(const ushort* __restrict__ Qb,
                const ushort* __restrict__ Kb,
                const ushort* __restrict__ VTb,
                ushort* __restrict__ Ob)
{
    __shared__ __align__(16) ushort Ks[2][64 * 64];
    __shared__ __align__(16) ushort Vs[2][64 * 64];
    __shared__ __align__(16) ushort P_lds[4][32 * 64];
    const int qt = (int)gridDim.x - 1 - (int)blockIdx.x;   // heavy tiles first
    const int h = blockIdx.y, b = blockIdx.z;
    const int kvh = h >> 2;
    const int tid = threadIdx.x;
    const int w = tid >> 6, lane = tid & 63;
    const int l15 = lane & 15, g = lane >> 4;

    const ushort* Qh = Qb + (((size_t)b * H_ + h) * T_ + qt * AQB + w * 32) * 64;
    const ushort* Kh = Kb + (((size_t)b * KV_ + kvh) * T_) * 64;
    const ushort* Vh = VTb + ((size_t)b * KV_ + kvh) * 64 * (size_t)T_;

    short8 qf[2][2];
#pragma unroll
    for (int m = 0; m < 2; ++m) {
        qf[m][0] = *reinterpret_cast<const short8*>(Qh + (m * 16 + l15) * 64 + g * 8);
        qf[m][1] = *reinterpret_cast<const short8*>(Qh + (m * 16 + l15) * 64 + 32 + g * 8);
    }

    f32x4 o4[2][4] = {};
    float m_[2][4] = {{-INFINITY, -INFINITY, -INFINITY, -INFINITY},
                      {-INFINITY, -INFINITY, -INFINITY, -INFINITY}};
    float l_[2][4] = {};
    ushort* Pw = P_lds[w];

    const int jend = 2 * qt + 1;
    stage_kv(Kh, Vh, Ks[0], Vs[0], 0, w, lane);
    __syncthreads();   // drains vmcnt: tile 0 resident

    int cur = 0;
    for (int j = 0; j <= jend; ++j) {
        if (j < jend)
            stage_kv(Kh, Vh, Ks[cur ^ 1], Vs[cur ^ 1], j + 1, w, lane);

        // ---- QK^T from swizzled K-LDS ----
        const ushort* Kc = Ks[cur];
        f32x4 s4[2][4] = {};
        __builtin_amdgcn_s_setprio(1);
#pragma unroll
        for (int kk = 0; kk < 2; ++kk) {
            short8 kf[4];
#pragma unroll
            for (int n = 0; n < 4; ++n) {
                const int row = n * 16 + l15;
                kf[n] = *reinterpret_cast<const short8*>(
                    &Kc[row * 64 + (((kk * 4 + g) ^ (row & 7)) << 3)]);
            }
#pragma unroll
            for (int m = 0; m < 2; ++m)
#pragma unroll
                for (int n = 0; n < 4; ++n)
                    s4[m][n] = __builtin_amdgcn_mfma_f32_16x16x32_bf16(qf[m][kk], kf[n], s4[m][n], 0, 0, 0);
        }
        __builtin_amdgcn_s_setprio(0);

        // ---- causal mask (Q pre-scaled by 1/sqrt(D) in prep) ----
        const bool diag = (j >= 2 * qt);
        if (diag) {
#pragma unroll
            for (int m = 0; m < 2; ++m) {
                const int rowq = qt * AQB + w * 32 + m * 16 + g * 4;
#pragma unroll
                for (int n = 0; n < 4; ++n) {
                    const int col = j * 64 + n * 16 + l15;
#pragma unroll
                    for (int r = 0; r < 4; ++r)
                        if (col > rowq + r) s4[m][n][r] = -1e30f;
                }
            }
        }

        // ---- online softmax (rows in (m, g, reg) space) ----
#pragma unroll
        for (int m = 0; m < 2; ++m)
#pragma unroll
            for (int r = 0; r < 4; ++r) {
                float tmax = fmaxf(fmaxf(s4[m][0][r], s4[m][1][r]),
                                   fmaxf(s4[m][2][r], s4[m][3][r]));
                tmax = fmaxf(tmax, __shfl_xor(tmax, 1));
                tmax = fmaxf(tmax, __shfl_xor(tmax, 2));
                tmax = fmaxf(tmax, __shfl_xor(tmax, 4));
                tmax = fmaxf(tmax, __shfl_xor(tmax, 8));
                const float mn = fmaxf(m_[m][r], tmax);
                const float sc = __expf(m_[m][r] - mn);
                float ps = 0.f;
#pragma unroll
                for (int n = 0; n < 4; ++n) {
                    float p = __expf(s4[m][n][r] - mn);
                    s4[m][n][r] = p;
                    ps += p;
                }
                ps += __shfl_xor(ps, 1);
                ps += __shfl_xor(ps, 2);
                ps += __shfl_xor(ps, 4);
                ps += __shfl_xor(ps, 8);
                l_[m][r] = l_[m][r] * sc + ps;
                m_[m][r] = mn;
#pragma unroll
                for (int n = 0; n < 4; ++n) o4[m][n][r] *= sc;
            }

        // ---- P -> bf16 -> swizzled wave-private LDS ----
#pragma unroll
        for (int m = 0; m < 2; ++m)
#pragma unroll
            for (int n = 0; n < 4; ++n)
#pragma unroll
                for (int r = 0; r < 4; ++r) {
                    const int row = m * 16 + g * 4 + r;
                    const int col = n * 16 + l15;
                    Pw[row * 64 + (col ^ ((row & 7) << 3))] = f2bf(s4[m][n][r]);
                }

        // ---- PV from swizzled P-LDS and V-LDS ----
        const ushort* Vc = Vs[cur];
        __builtin_amdgcn_s_setprio(1);
#pragma unroll
        for (int kk = 0; kk < 2; ++kk) {
            short8 pf[2];
#pragma unroll
            for (int m = 0; m < 2; ++m) {
                const int row = m * 16 + l15;
                pf[m] = *reinterpret_cast<const short8*>(
                    &Pw[row * 64 + (((kk * 4 + g) ^ (row & 7)) << 3)]);
            }
            short8 vf[4];
#pragma unroll
            for (int n = 0; n < 4; ++n) {
                const int row = n * 16 + l15;
                vf[n] = *reinterpret_cast<const short8*>(
                    &Vc[row * 64 + (((kk * 4 + g) ^ (row & 7)) << 3)]);
            }
#pragma unroll
            for (int m = 0; m < 2; ++m)
#pragma unroll
                for (int n = 0; n < 4; ++n)
                    o4[m][n] = __builtin_amdgcn_mfma_f32_16x16x32_bf16(pf[m], vf[n], o4[m][n], 0, 0, 0);
        }
        __builtin_amdgcn_s_setprio(0);

        __syncthreads();   // next tile staged (vmcnt drained) + buffers free
        cur ^= 1;
    }

    // ---- epilogue: O[b][t][h][d] bf16 ----
#pragma unroll
    for (int m = 0; m < 2; ++m)
#pragma unroll
        for (int r = 0; r < 4; ++r) {
            const float inv = 1.f / l_[m][r];
            const int tg = qt * AQB + w * 32 + m * 16 + g * 4 + r;
            ushort* op = Ob + ((size_t)b * T_ + tg) * QW + h * 64;
#pragma unroll
            for (int n = 0; n < 4; ++n)
                op[n * 16 + l15] = f2bf(o4[m][n][r] * inv);
        }
}

// ---------------------------------------------------------------------------
// Workspace layout (88 MB high-water):
//   xb / Obf bf16 [4096][2048] @ 0         (16 MB)
//   WT   bf16 [3072][2048]     @ 16777216  (12 MB)
//   WTo  bf16 [2048][2048]     @ 29360128  ( 8 MB)
//   QKVb bf16 [4096][3072]     @ 37748736  (24 MB)
//   Qbf  bf16 [b][h][t][64]    @ 62914560  (16 MB)
//   Kbf  bf16 [b][kv][t][64]   @ 79691776  ( 4 MB)
//   VT   bf16 [b][kv][64][t]   @ 83886080  ( 4 MB)
// ---------------------------------------------------------------------------
extern "C" void kernel_launch(void* const* d_in, const int* in_sizes, int n_in,
                              void* d_out, int out_size, void* d_ws, size_t ws_size,
                              hipStream_t stream)
{
    const float* x  = (const float*)d_in[0];
    const float* fc = (const float*)d_in[1];
    const float* Wq = (const float*)d_in[2];
    const float* Wk = (const float*)d_in[3];
    const float* Wv = (const float*)d_in[4];
    const float* Wo = (const float*)d_in[5];
    float* out = (float*)d_out;

    char* ws = (char*)d_ws;
    ushort* xb   = (ushort*)(ws);
    ushort* WT   = (ushort*)(ws + 16777216);
    ushort* WTo  = (ushort*)(ws + 29360128);
    ushort* QKVb = (ushort*)(ws + 37748736);
    ushort* Qbf  = (ushort*)(ws + 62914560);
    ushort* Kbf  = (ushort*)(ws + 79691776);
    ushort* VT   = (ushort*)(ws + 83886080);
    ushort* Obf  = xb;   // xb dead after QKV gemm

    // 1) casts + weight transposes (bf16)
    cast_bf16<<<4096, 256, 0, stream>>>(x, xb);
    transcast<<<dim3(32, 32), 256, 0, stream>>>(Wq, WT, E_, QW);
    transcast<<<dim3( 8, 32), 256, 0, stream>>>(Wk, WT + (size_t)2048 * 2048, E_, KW);
    transcast<<<dim3( 8, 32), 256, 0, stream>>>(Wv, WT + (size_t)2560 * 2048, E_, KW);
    transcast<<<dim3(32, 32), 256, 0, stream>>>(Wo, WTo, QW, E_);

    // 2) fused QKV projection (bf16 MFMA): xb @ WT^T -> QKVb [4096][3072]
    gemm_bt<true><<<dim3(NQKV / 128, NROW / 128), 256, 0, stream>>>(xb, WT, QKVb, NQKV, E_);

    // 3) RoPE (Q pre-scaled) + head-major re-layout; V transpose
    prep_qk<<<TPAIRS / 256, 256, 0, stream>>>(QKVb, fc, Qbf, Kbf);
    transpose_v<<<dim3(T_ / 64, B_ * KV_), 256, 0, stream>>>(QKVb, VT);

    // 4) causal GQA flash attention v2 -> Obf bf16 [4096][2048]
    attn_mfma2<<<dim3(T_ / AQB, H_, B_), 256, 0, stream>>>(Qbf, Kbf, VT, Obf);

    // 5) output projection (bf16 MFMA, fp32 out): Obf @ WTo^T -> out
    gemm_bt<false><<<dim3(E_ / 128, NROW / 128), 256, 0, stream>>>(Obf, WTo, out, E_, E_);
}

// Round 7
// 406.401 us; speedup vs baseline: 15.9832x; 1.1608x over previous
//
#include <hip/hip_runtime.h>
#include <hip/hip_bf16.h>
#include <math.h>

// Problem constants (GroupedQueryAttention: B=2,T=2048,E=2048,H=32,KV=8,D=64,R=4)
#define B_   2
#define T_   2048
#define E_   2048
#define H_   32
#define KV_  8
#define D_   64
#define NROW (B_*T_)          // 4096 rows of x
#define QW   (H_*D_)          // 2048
#define KW   (KV_*D_)         // 512
#define NQKV 3072             // fused [Q|K|V] projection width

typedef __attribute__((ext_vector_type(8))) short short8;
typedef __attribute__((ext_vector_type(4))) float f32x4;

__device__ __forceinline__ ushort f2bf(float f) {
    __hip_bfloat16 h = __float2bfloat16(f);
    return *reinterpret_cast<ushort*>(&h);
}
__device__ __forceinline__ float bf2f(ushort u) {
    union { unsigned int i; float f; } v; v.i = ((unsigned int)u) << 16; return v.f;
}
__device__ __forceinline__ uint pack_bf16(float lo, float hi) {
    return (uint)f2bf(lo) | ((uint)f2bf(hi) << 16);
}

// async global->LDS, 16B per lane. LDS dest must be wave-uniform base (+lane*16).
__device__ __forceinline__ void gload_lds16(const ushort* g, ushort* l) {
    __builtin_amdgcn_global_load_lds(
        (const __attribute__((address_space(1))) void*)g,
        (__attribute__((address_space(3))) void*)l,
        16, 0, 0);
}

// ---------------------------------------------------------------------------
// cast_bf16: fp32 -> bf16, 8 elems/thread
// ---------------------------------------------------------------------------
__global__ __launch_bounds__(256)
void cast_bf16(const float* __restrict__ src, ushort* __restrict__ dst)
{
    const size_t i = ((size_t)blockIdx.x * 256 + threadIdx.x) * 8;
    float4 v0 = *reinterpret_cast<const float4*>(src + i);
    float4 v1 = *reinterpret_cast<const float4*>(src + i + 4);
    ushort o[8] = {f2bf(v0.x), f2bf(v0.y), f2bf(v0.z), f2bf(v0.w),
                   f2bf(v1.x), f2bf(v1.y), f2bf(v1.z), f2bf(v1.w)};
    *reinterpret_cast<short8*>(dst + i) = *reinterpret_cast<const short8*>(o);
}

// ---------------------------------------------------------------------------
// transcast: src fp32 [R][C] row-major -> dst bf16 [C][R] (weight transpose).
// ---------------------------------------------------------------------------
__global__ __launch_bounds__(256)
void transcast(const float* __restrict__ src, ushort* __restrict__ dst, int R, int C)
{
    __shared__ float tile[64][65];
    const int r0 = blockIdx.y * 64, c0 = blockIdx.x * 64;
    const int tid = threadIdx.x;
    const int cc = tid & 63, rb = tid >> 6;
#pragma unroll
    for (int i = 0; i < 16; ++i) {
        int r = rb + i * 4;
        tile[r][cc] = src[(size_t)(r0 + r) * C + c0 + cc];
    }
    __syncthreads();
#pragma unroll
    for (int i = 0; i < 16; ++i) {
        int rr = rb + i * 4;
        dst[(size_t)(c0 + rr) * R + r0 + cc] = f2bf(tile[cc][rr]);
    }
}

// ---------------------------------------------------------------------------
// gemm_bt: C[M x N] = A[M x K](bf16) * BT[N x K](bf16)^T, fp32 accum.
// m97 structure (unchanged).
// ---------------------------------------------------------------------------
template<bool BF16OUT>
__global__ __launch_bounds__(256)
void gemm_bt(const ushort* __restrict__ A, const ushort* __restrict__ BT,
             void* __restrict__ Cv, int N, int K)
{
    __shared__ __align__(16) ushort As[128 * 32];
    __shared__ __align__(16) ushort Bs[128 * 32];
    const int tid = threadIdx.x;
    const int w = tid >> 6, lane = tid & 63;
    const int l15 = lane & 15, g = lane >> 4;
    const int wr = w >> 1, wc = w & 1;
    const size_t brow = (size_t)blockIdx.y * 128, bcol = (size_t)blockIdx.x * 128;

    f32x4 acc[4][4] = {};

    const int srow = w * 32 + (lane >> 2);
    const int skc  = (lane & 3) * 8;
    const ushort* gA = A  + (brow + srow) * K + skc;
    const ushort* gB = BT + (bcol + srow) * K + skc;
    ushort* lA = &As[(w * 32) * 32];
    ushort* lB = &Bs[(w * 32) * 32];

    for (int k0 = 0; k0 < K; k0 += 32) {
        gload_lds16(gA + k0,                  lA);
        gload_lds16(gA + k0 + (size_t)16 * K, lA + 16 * 32);
        gload_lds16(gB + k0,                  lB);
        gload_lds16(gB + k0 + (size_t)16 * K, lB + 16 * 32);
        __syncthreads();

        short8 a[4], b[4];
#pragma unroll
        for (int m = 0; m < 4; ++m)
            a[m] = *reinterpret_cast<const short8*>(&As[(wr * 64 + m * 16 + l15) * 32 + g * 8]);
#pragma unroll
        for (int n = 0; n < 4; ++n)
            b[n] = *reinterpret_cast<const short8*>(&Bs[(wc * 64 + n * 16 + l15) * 32 + g * 8]);
#pragma unroll
        for (int m = 0; m < 4; ++m)
#pragma unroll
            for (int n = 0; n < 4; ++n)
                acc[m][n] = __builtin_amdgcn_mfma_f32_16x16x32_bf16(a[m], b[n], acc[m][n], 0, 0, 0);
        __syncthreads();
    }

#pragma unroll
    for (int m = 0; m < 4; ++m) {
#pragma unroll
        for (int r = 0; r < 4; ++r) {
            const size_t row = brow + wr * 64 + m * 16 + g * 4 + r;
#pragma unroll
            for (int n = 0; n < 4; ++n) {
                const size_t col = bcol + wc * 64 + n * 16 + l15;
                if (BF16OUT) ((ushort*)Cv)[row * N + col] = f2bf(acc[m][n][r]);
                else         ((float*) Cv)[row * N + col] = acc[m][n][r];
            }
        }
    }
}

// ---------------------------------------------------------------------------
// prep_qk: RoPE + head-major re-layout; Q pre-scaled by 1/sqrt(D).
// ---------------------------------------------------------------------------
#define QPAIRS (NROW * H_  * 32)
#define KPAIRS (NROW * KV_ * 32)
#define TPAIRS (QPAIRS + KPAIRS)

__global__ __launch_bounds__(256)
void prep_qk(const ushort* __restrict__ QKVb, const float* __restrict__ fc,
             ushort* __restrict__ Qb, ushort* __restrict__ Kb)
{
    int idx = blockIdx.x * 256 + threadIdx.x;
    if (idx < QPAIRS) {
        int p = idx & 31;
        int t = (idx >> 5) & (T_ - 1);
        int bh = idx >> 16;
        int h = bh & (H_ - 1), b = bh >> 5;
        ushort2 ab = *reinterpret_cast<const ushort2*>(
            QKVb + (size_t)(b * T_ + t) * NQKV + h * 64 + p * 2);
        float c = fc[t * 64 + p * 2], s = fc[t * 64 + p * 2 + 1];
        float x0 = bf2f(ab.x), x1 = bf2f(ab.y);
        ushort2 pk;
        pk.x = f2bf((x0 * c - x1 * s) * 0.125f);
        pk.y = f2bf((x0 * s + x1 * c) * 0.125f);
        *reinterpret_cast<ushort2*>(Qb + (size_t)idx * 2) = pk;
    } else {
        int i2 = idx - QPAIRS;
        int p = i2 & 31;
        int t = (i2 >> 5) & (T_ - 1);
        int bk = i2 >> 16;
        int kh = bk & 7, b = bk >> 3;
        ushort2 ab = *reinterpret_cast<const ushort2*>(
            QKVb + (size_t)(b * T_ + t) * NQKV + 2048 + kh * 64 + p * 2);
        float c = fc[t * 64 + p * 2], s = fc[t * 64 + p * 2 + 1];
        float x0 = bf2f(ab.x), x1 = bf2f(ab.y);
        ushort2 pk;
        pk.x = f2bf(x0 * c - x1 * s);
        pk.y = f2bf(x0 * s + x1 * c);
        *reinterpret_cast<ushort2*>(Kb + (size_t)i2 * 2) = pk;
    }
}

// ---------------------------------------------------------------------------
// transpose_v: QKV V-slice bf16 [b t][kvh d] -> VT bf16 [b][kvh][d][t]
// ---------------------------------------------------------------------------
__global__ __launch_bounds__(256)
void transpose_v(const ushort* __restrict__ QKVb, ushort* __restrict__ VT)
{
    __shared__ ushort tile[64][65];
    const int t0 = blockIdx.x * 64;
    const int bk = blockIdx.y;
    const int b = bk >> 3, kh = bk & 7;
    const int tid = threadIdx.x;
    const int c = tid & 63, rbase = tid >> 6;
#pragma unroll
    for (int i = 0; i < 16; ++i) {
        int r = rbase + i * 4;
        tile[r][c] = QKVb[(size_t)(b * T_ + t0 + r) * NQKV + 2560 + kh * 64 + c];
    }
    __syncthreads();
#pragma unroll
    for (int i = 0; i < 16; ++i) {
        int d = rbase + i * 4;
        VT[((size_t)bk * 64 + d) * T_ + t0 + c] = tile[c][d];
    }
}

// ---------------------------------------------------------------------------
// Flash attention v3: SWAPPED QK^T (S^T = K·Q^T, col = q = lane-local).
// grid = (T/128, H, B), 256 threads (4 waves); wave w owns q rows
// [w*32, w*32+32) as two 16-col fragment sets (nQ).
//
// Layouts (all verified forms):
//   A/B-frag: idx = lane&15, k = (lane>>4)*8+i ;  C/D: col = lane&15,
//   row = (lane>>4)*4 + reg.
// QK^T:  S^T[kv][q] = mfma(K-frag, Q-frag)    -> lane holds 16 kv scores
//        (mK=0..3, r=0..3 ; kv = mK*16+g*4+r) for q = nQ*16+l15.
// Softmax: in-lane tree (15 ops) + shfl_xor(16)+shfl_xor(32). Lane-local
//        m/l state per q.
// P:     bf16 P[q][kv] in wave-private LDS, pair-packed ds_write_b64,
//        16B-chunk XOR swizzle (chunk ^= q&7) on both write and read.
// PV:    O^T[d][q] = mfma(V^T-frag(rows=d), P^T-frag(col=q)) -> rescale and
//        1/l stay lane-local.
// Epilogue: O^T regs -> wave-private LDS (same swizzle) -> coalesced 16B
//        global stores.
// ---------------------------------------------------------------------------
__device__ __forceinline__
void stage_kv(const ushort* __restrict__ Kh, const ushort* __restrict__ Vh,
              ushort* lK, ushort* lV, int j, int w, int lane)
{
    const int rsub = lane >> 3;          // 0..7
    const int sc   = (lane & 7) ^ rsub;  // inverse-swizzled source chunk
#pragma unroll
    for (int it = 0; it < 2; ++it) {
        const int row = w * 16 + it * 8 + rsub;          // 0..63
        gload_lds16(Kh + ((size_t)(j * 64 + row)) * 64 + sc * 8,
                    lK + (w * 16 + it * 8) * 64);
        gload_lds16(Vh + (size_t)row * T_ + j * 64 + sc * 8,
                    lV + (w * 16 + it * 8) * 64);
    }
}

#define AQB 128   // q rows per attention block

__global__ __launch_bounds__(256)
void attn_mfma3(const ushort* __restrict__ Qb,
                const ushort* __restrict__ Kb,
                const ushort* __restrict__ VTb,
                ushort* __restrict__ Ob)
{
    __shared__ __align__(16) ushort Ks[2][64 * 64];
    __shared__ __align__(16) ushort Vs[2][64 * 64];
    __shared__ __align__(16) ushort P_lds[4][32 * 64];   // wave-private 4KB
    const int qt = (int)gridDim.x - 1 - (int)blockIdx.x;   // heavy tiles first
    const int h = blockIdx.y, b = blockIdx.z;
    const int kvh = h >> 2;
    const int tid = threadIdx.x;
    const int w = tid >> 6, lane = tid & 63;
    const int l15 = lane & 15, g = lane >> 4;
    const int sw = l15 & 7;

    const ushort* Qh = Qb + (((size_t)b * H_ + h) * T_ + qt * AQB + w * 32) * 64;
    const ushort* Kh = Kb + (((size_t)b * KV_ + kvh) * T_) * 64;
    const ushort* Vh = VTb + ((size_t)b * KV_ + kvh) * 64 * (size_t)T_;

    // Q fragments (B-operand): q = nQ*16 + l15, k(d) = kk*32 + g*8 + i
    short8 qf[2][2];
#pragma unroll
    for (int nQ = 0; nQ < 2; ++nQ) {
        qf[nQ][0] = *reinterpret_cast<const short8*>(Qh + (nQ * 16 + l15) * 64 + g * 8);
        qf[nQ][1] = *reinterpret_cast<const short8*>(Qh + (nQ * 16 + l15) * 64 + 32 + g * 8);
    }

    f32x4 o4[4][2] = {};                   // O^T: [mD][nQ], col=q=l15, row=d=g*4+r
    float m_[2] = {-INFINITY, -INFINITY};  // per-q (lane-local) running max
    float l_[2] = {0.f, 0.f};
    ushort* Pw = P_lds[w];

    const int qmax_w = qt * AQB + w * 32 + 31;   // wave's last q row
    const int jend = 2 * qt + 1;
    stage_kv(Kh, Vh, Ks[0], Vs[0], 0, w, lane);
    __syncthreads();

    int cur = 0;
    for (int j = 0; j <= jend; ++j) {
        if (j < jend)
            stage_kv(Kh, Vh, Ks[cur ^ 1], Vs[cur ^ 1], j + 1, w, lane);

        if (j * 64 <= qmax_w) {   // wave has at least one unmasked column
            // ---- S^T = K · Q^T from swizzled K-LDS ----
            const ushort* Kc = Ks[cur];
            f32x4 s4[2][4] = {};   // [nQ][mK]
            __builtin_amdgcn_s_setprio(1);
#pragma unroll
            for (int kk = 0; kk < 2; ++kk) {
                short8 kf[4];
#pragma unroll
                for (int mK = 0; mK < 4; ++mK) {
                    const int row = mK * 16 + l15;
                    kf[mK] = *reinterpret_cast<const short8*>(
                        &Kc[row * 64 + (((kk * 4 + g) ^ (row & 7)) << 3)]);
                }
#pragma unroll
                for (int nQ = 0; nQ < 2; ++nQ)
#pragma unroll
                    for (int mK = 0; mK < 4; ++mK)
                        s4[nQ][mK] = __builtin_amdgcn_mfma_f32_16x16x32_bf16(
                            kf[mK], qf[nQ][kk], s4[nQ][mK], 0, 0, 0);
            }
            __builtin_amdgcn_s_setprio(0);

            // ---- causal mask: kv > q -> -inf ----
            if (j * 64 + 63 > qt * AQB + w * 32) {
#pragma unroll
                for (int nQ = 0; nQ < 2; ++nQ) {
                    const int qg = qt * AQB + w * 32 + nQ * 16 + l15;
#pragma unroll
                    for (int mK = 0; mK < 4; ++mK) {
                        const int kv0 = j * 64 + mK * 16 + g * 4;
#pragma unroll
                        for (int r = 0; r < 4; ++r)
                            if (kv0 + r > qg) s4[nQ][mK][r] = -1e30f;
                    }
                }
            }

            // ---- online softmax: in-lane tree + 2 shfl; state lane-local ----
#pragma unroll
            for (int nQ = 0; nQ < 2; ++nQ) {
                float tm = fmaxf(fmaxf(fmaxf(s4[nQ][0][0], s4[nQ][0][1]),
                                       fmaxf(s4[nQ][0][2], s4[nQ][0][3])),
                                 fmaxf(fmaxf(s4[nQ][1][0], s4[nQ][1][1]),
                                       fmaxf(s4[nQ][1][2], s4[nQ][1][3])));
                tm = fmaxf(tm, fmaxf(fmaxf(fmaxf(s4[nQ][2][0], s4[nQ][2][1]),
                                           fmaxf(s4[nQ][2][2], s4[nQ][2][3])),
                                     fmaxf(fmaxf(s4[nQ][3][0], s4[nQ][3][1]),
                                           fmaxf(s4[nQ][3][2], s4[nQ][3][3]))));
                tm = fmaxf(tm, __shfl_xor(tm, 16));
                tm = fmaxf(tm, __shfl_xor(tm, 32));
                const float mn = fmaxf(m_[nQ], tm);
                const float sc = __expf(m_[nQ] - mn);
                float ps = 0.f;
#pragma unroll
                for (int mK = 0; mK < 4; ++mK) {
                    float p0 = __expf(s4[nQ][mK][0] - mn);
                    float p1 = __expf(s4[nQ][mK][1] - mn);
                    float p2 = __expf(s4[nQ][mK][2] - mn);
                    float p3 = __expf(s4[nQ][mK][3] - mn);
                    s4[nQ][mK][0] = p0; s4[nQ][mK][1] = p1;
                    s4[nQ][mK][2] = p2; s4[nQ][mK][3] = p3;
                    ps += (p0 + p1) + (p2 + p3);
                }
                ps += __shfl_xor(ps, 16);
                ps += __shfl_xor(ps, 32);
                l_[nQ] = l_[nQ] * sc + ps;
                m_[nQ] = mn;
#pragma unroll
                for (int mD = 0; mD < 4; ++mD)
#pragma unroll
                    for (int r = 0; r < 4; ++r)
                        o4[mD][nQ][r] *= sc;
            }

            // ---- P[q][kv] -> wave-private swizzled LDS (8 x ds_write_b64) ----
#pragma unroll
            for (int nQ = 0; nQ < 2; ++nQ) {
                const int rowi = (nQ * 16 + l15) * 64;
#pragma unroll
                for (int mK = 0; mK < 4; ++mK) {
                    uint2 wv;
                    wv.x = pack_bf16(s4[nQ][mK][0], s4[nQ][mK][1]);
                    wv.y = pack_bf16(s4[nQ][mK][2], s4[nQ][mK][3]);
                    const int idx = rowi + ((((2 * mK + (g >> 1)) ^ sw) << 3) + (g & 1) * 4);
                    *reinterpret_cast<uint2*>(&Pw[idx]) = wv;
                }
            }

            // ---- O^T += V^T · P^T ----
            const ushort* Vc = Vs[cur];
            __builtin_amdgcn_s_setprio(1);
#pragma unroll
            for (int kk = 0; kk < 2; ++kk) {
                short8 pb[2];
#pragma unroll
                for (int nQ = 0; nQ < 2; ++nQ)
                    pb[nQ] = *reinterpret_cast<const short8*>(
                        &Pw[(nQ * 16 + l15) * 64 + (((4 * kk + g) ^ sw) << 3)]);
                short8 af[4];
#pragma unroll
                for (int mD = 0; mD < 4; ++mD) {
                    const int row = mD * 16 + l15;
                    af[mD] = *reinterpret_cast<const short8*>(
                        &Vc[row * 64 + (((kk * 4 + g) ^ (row & 7)) << 3)]);
                }
#pragma unroll
                for (int mD = 0; mD < 4; ++mD)
#pragma unroll
                    for (int nQ = 0; nQ < 2; ++nQ)
                        o4[mD][nQ] = __builtin_amdgcn_mfma_f32_16x16x32_bf16(
                            af[mD], pb[nQ], o4[mD][nQ], 0, 0, 0);
            }
            __builtin_amdgcn_s_setprio(0);
        }

        __syncthreads();
        cur ^= 1;
    }

    // ---- epilogue: O^T regs -> swizzled wave-private LDS -> coalesced store ----
    const float inv[2] = {1.f / l_[0], 1.f / l_[1]};
#pragma unroll
    for (int nQ = 0; nQ < 2; ++nQ) {
        const int rowi = (nQ * 16 + l15) * 64;
#pragma unroll
        for (int mD = 0; mD < 4; ++mD) {
            uint2 wv;
            wv.x = pack_bf16(o4[mD][nQ][0] * inv[nQ], o4[mD][nQ][1] * inv[nQ]);
            wv.y = pack_bf16(o4[mD][nQ][2] * inv[nQ], o4[mD][nQ][3] * inv[nQ]);
            const int idx = rowi + ((((2 * mD + (g >> 1)) ^ sw) << 3) + (g & 1) * 4);
            *reinterpret_cast<uint2*>(&Pw[idx]) = wv;
        }
    }
    // wave-private: lgkmcnt ordering suffices, no barrier.
#pragma unroll
    for (int p4 = 0; p4 < 4; ++p4) {
        const int q2 = p4 * 8 + (lane >> 3);     // 0..31
        const int c  = lane & 7;                 // 16B chunk within the 128B row
        short8 v = *reinterpret_cast<const short8*>(
            &Pw[q2 * 64 + (((c ^ (q2 & 7)) << 3))]);
        const int qg = qt * AQB + w * 32 + q2;
        *reinterpret_cast<short8*>(Ob + ((size_t)b * T_ + qg) * QW + h * 64 + c * 8) = v;
    }
}

// ---------------------------------------------------------------------------
// Workspace layout (88 MB high-water):
//   xb / Obf bf16 [4096][2048] @ 0         (16 MB)
//   WT   bf16 [3072][2048]     @ 16777216  (12 MB)
//   WTo  bf16 [2048][2048]     @ 29360128  ( 8 MB)
//   QKVb bf16 [4096][3072]     @ 37748736  (24 MB)
//   Qbf  bf16 [b][h][t][64]    @ 62914560  (16 MB)
//   Kbf  bf16 [b][kv][t][64]   @ 79691776  ( 4 MB)
//   VT   bf16 [b][kv][64][t]   @ 83886080  ( 4 MB)
// ---------------------------------------------------------------------------
extern "C" void kernel_launch(void* const* d_in, const int* in_sizes, int n_in,
                              void* d_out, int out_size, void* d_ws, size_t ws_size,
                              hipStream_t stream)
{
    const float* x  = (const float*)d_in[0];
    const float* fc = (const float*)d_in[1];
    const float* Wq = (const float*)d_in[2];
    const float* Wk = (const float*)d_in[3];
    const float* Wv = (const float*)d_in[4];
    const float* Wo = (const float*)d_in[5];
    float* out = (float*)d_out;

    char* ws = (char*)d_ws;
    ushort* xb   = (ushort*)(ws);
    ushort* WT   = (ushort*)(ws + 16777216);
    ushort* WTo  = (ushort*)(ws + 29360128);
    ushort* QKVb = (ushort*)(ws + 37748736);
    ushort* Qbf  = (ushort*)(ws + 62914560);
    ushort* Kbf  = (ushort*)(ws + 79691776);
    ushort* VT   = (ushort*)(ws + 83886080);
    ushort* Obf  = xb;   // xb dead after QKV gemm

    // 1) casts + weight transposes (bf16)
    cast_bf16<<<4096, 256, 0, stream>>>(x, xb);
    transcast<<<dim3(32, 32), 256, 0, stream>>>(Wq, WT, E_, QW);
    transcast<<<dim3( 8, 32), 256, 0, stream>>>(Wk, WT + (size_t)2048 * 2048, E_, KW);
    transcast<<<dim3( 8, 32), 256, 0, stream>>>(Wv, WT + (size_t)2560 * 2048, E_, KW);
    transcast<<<dim3(32, 32), 256, 0, stream>>>(Wo, WTo, QW, E_);

    // 2) fused QKV projection (bf16 MFMA): xb @ WT^T -> QKVb [4096][3072]
    gemm_bt<true><<<dim3(NQKV / 128, NROW / 128), 256, 0, stream>>>(xb, WT, QKVb, NQKV, E_);

    // 3) RoPE (Q pre-scaled) + head-major re-layout; V transpose
    prep_qk<<<TPAIRS / 256, 256, 0, stream>>>(QKVb, fc, Qbf, Kbf);
    transpose_v<<<dim3(T_ / 64, B_ * KV_), 256, 0, stream>>>(QKVb, VT);

    // 4) causal GQA flash attention v3 (swapped QK^T) -> Obf bf16 [4096][2048]
    attn_mfma3<<<dim3(T_ / AQB, H_, B_), 256, 0, stream>>>(Qbf, Kbf, VT, Obf);

    // 5) output projection (bf16 MFMA, fp32 out): Obf @ WTo^T -> out
    gemm_bt<false><<<dim3(E_ / 128, NROW / 128), 256, 0, stream>>>(Obf, WTo, out, E_, E_);
}